// Round 2
// baseline (290.534 us; speedup 1.0000x reference)
//
#include <hip/hip_runtime.h>

// ---------------- types / helpers ----------------
typedef __bf16 bf16;
typedef __attribute__((ext_vector_type(8)))  bf16     bf16x8;
typedef __attribute__((ext_vector_type(4)))  bf16     bf16x4;
typedef __attribute__((ext_vector_type(16))) float    f32x16;
typedef __attribute__((ext_vector_type(4)))  float    f32x4;
typedef __attribute__((ext_vector_type(4)))  unsigned uint4v;

#define SLEN 4096
#define NHEAD 8
#define HDIM 64
#define EMB 512
#define LOG2E 1.4426950408889634f
#define NEGBIG -1.25e19f  /* -1e20/8 : mask applied BEFORE 1/sqrt(d) scale */

__device__ __forceinline__ f32x16 mfma32(bf16x8 a, bf16x8 b, f32x16 c) {
  return __builtin_amdgcn_mfma_f32_32x32x16_bf16(a, b, c, 0, 0, 0);
}

// async global->LDS, 16B per lane; LDS dest is wave-uniform base + lane*16
__device__ __forceinline__ void cp16(const void* g, const void* l) {
  __builtin_amdgcn_global_load_lds(
      (__attribute__((address_space(1))) unsigned int*)(unsigned long long)g,
      (__attribute__((address_space(3))) unsigned int*)(unsigned int)(unsigned long long)l,
      16, 0, 0);
}

__device__ __forceinline__ unsigned pk2(float a, float b) {
  unsigned short ua = __builtin_bit_cast(unsigned short, (bf16)a);
  unsigned short ub = __builtin_bit_cast(unsigned short, (bf16)b);
  return (unsigned)ua | ((unsigned)ub << 16);
}

// ---------------- kernel 1: QKV projections (MFMA) ----------------
// X (fp32) viewed as [65536][64] rows (row = (b*S+s)*8 + h, cols = within-head dim).
// q = X @ Wq^T : D[m=row][n=i] = sum_j X[row][j] * Wq[i][j].
// Writes Qb/Kb as bf16 [BH][S][64], V transposed VT as bf16 [BH][64][S].
__global__ __launch_bounds__(256, 2) void proj_qkv(
    const float* __restrict__ key, const float* __restrict__ query, const float* __restrict__ value,
    const float* __restrict__ Wq, const float* __restrict__ Wk, const float* __restrict__ Wv,
    bf16* __restrict__ Qb, bf16* __restrict__ Kb, bf16* __restrict__ VT)
{
  __shared__ __align__(16) bf16 tile[128][64];
  const int tid = threadIdx.x, w = tid >> 6, lane = tid & 63, l31 = lane & 31, lh = lane >> 5;
  const int r0 = blockIdx.x * 128;
  const int m0 = r0 + w * 32;

  #pragma unroll
  for (int p = 0; p < 3; ++p) {
    const float* X = (p == 0) ? query : (p == 1) ? key : value;
    const float* W = (p == 0) ? Wq    : (p == 1) ? Wk  : Wv;

    // A fragments: lane&31 = row, k-slot = 16c + 8*lh + j (consistent map)
    bf16x8 af[4];
    {
      const float* xr = X + (size_t)(m0 + l31) * 64 + 8 * lh;
      #pragma unroll
      for (int c = 0; c < 4; ++c) {
        f32x4 lo = *(const f32x4*)(xr + c * 16);
        f32x4 hi = *(const f32x4*)(xr + c * 16 + 4);
        bf16x8 v;
        #pragma unroll
        for (int j = 0; j < 4; ++j) { v[j] = (bf16)lo[j]; v[4 + j] = (bf16)hi[j]; }
        af[c] = v;
      }
    }
    // B fragments: lane&31 = output col i (2 n-blocks), same k-slot map
    bf16x8 bfr[2][4];
    #pragma unroll
    for (int nb = 0; nb < 2; ++nb) {
      const float* wr = W + (size_t)(l31 + 32 * nb) * 64 + 8 * lh;
      #pragma unroll
      for (int c = 0; c < 4; ++c) {
        f32x4 lo = *(const f32x4*)(wr + c * 16);
        f32x4 hi = *(const f32x4*)(wr + c * 16 + 4);
        bf16x8 v;
        #pragma unroll
        for (int j = 0; j < 4; ++j) { v[j] = (bf16)lo[j]; v[4 + j] = (bf16)hi[j]; }
        bfr[nb][c] = v;
      }
    }
    f32x16 a0, a1;
    #pragma unroll
    for (int r = 0; r < 16; ++r) { a0[r] = 0.f; a1[r] = 0.f; }
    #pragma unroll
    for (int c = 0; c < 4; ++c) {
      a0 = mfma32(af[c], bfr[0][c], a0);
      a1 = mfma32(af[c], bfr[1][c], a1);
    }

    __syncthreads();  // protect previous iteration's tile reads
    // C/D layout: col = lane&31, row = (r&3)+8*(r>>2)+4*(lane>>5)
    #pragma unroll
    for (int r = 0; r < 16; ++r) {
      const int row = w * 32 + (r & 3) + 8 * (r >> 2) + 4 * lh;
      tile[row][l31]      = (bf16)a0[r];
      tile[row][l31 + 32] = (bf16)a1[r];
    }
    __syncthreads();

    if (p < 2) {
      bf16* OUT = p ? Kb : Qb;
      const int rloc = tid >> 1, half = tid & 1;
      const int rg = r0 + rloc, bs = rg >> 3, h = rg & 7, b = bs >> 12, sidx = bs & 4095;
      bf16* dst = OUT + (((size_t)(b * 8 + h) * SLEN + sidx) * 64 + half * 32);
      const bf16* srcp = &tile[rloc][half * 32];
      #pragma unroll
      for (int u = 0; u < 4; ++u) *(uint4v*)(dst + u * 8) = *(const uint4v*)(srcp + u * 8);
    } else {
      // V: transpose to VT [BH][64][S]
      const int h = tid >> 5, d0 = tid & 31;
      const int b = blockIdx.x >> 8, s0 = (blockIdx.x * 16) & 4095;
      #pragma unroll
      for (int dh = 0; dh < 2; ++dh) {
        const int dd = d0 + 32 * dh;
        unsigned pk4[8];
        #pragma unroll
        for (int t2 = 0; t2 < 8; ++t2) {
          unsigned short ua = __builtin_bit_cast(unsigned short, tile[(2 * t2) * 8 + h][dd]);
          unsigned short ub = __builtin_bit_cast(unsigned short, tile[(2 * t2 + 1) * 8 + h][dd]);
          pk4[t2] = (unsigned)ua | ((unsigned)ub << 16);
        }
        bf16* dst = VT + ((size_t)(b * 8 + h) * 64 + dd) * SLEN + s0;
        uint4v A; A[0] = pk4[0]; A[1] = pk4[1]; A[2] = pk4[2]; A[3] = pk4[3];
        uint4v Bv; Bv[0] = pk4[4]; Bv[1] = pk4[5]; Bv[2] = pk4[6]; Bv[3] = pk4[7];
        *(uint4v*)(dst) = A;
        *(uint4v*)(dst + 8) = Bv;
      }
    }
  }
}

// ---------------- kernel 2: mask -> bitmask ----------------
// MB[q][wi] bit l = (mask[q][wi*64+l] != 0)
__global__ void pack_mask(const int* __restrict__ mask, unsigned long long* __restrict__ MB)
{
  const int w = threadIdx.x >> 6, lane = threadIdx.x & 63;
  const int q = blockIdx.x * 4 + w;
  const int* row = mask + (size_t)q * SLEN;
  unsigned long long mine = 0ull;
  #pragma unroll 4
  for (int i = 0; i < 64; ++i) {
    unsigned long long b = __ballot(row[i * 64 + lane] != 0);
    if (i == lane) mine = b;
  }
  MB[(size_t)q * 64 + lane] = mine;
}

// ---------------- kernel 3: Wo -> hi/lo bf16 planes ----------------
__global__ void wo_split(const float* __restrict__ Wo, bf16* __restrict__ WH, bf16* __restrict__ WL)
{
  const int i = (blockIdx.x * 256 + threadIdx.x) * 4;
  f32x4 v = *(const f32x4*)(Wo + i);
  bf16x4 h, l;
  #pragma unroll
  for (int j = 0; j < 4; ++j) { h[j] = (bf16)v[j]; l[j] = (bf16)(v[j] - (float)h[j]); }
  *(bf16x4*)(WH + i) = h;
  *(bf16x4*)(WL + i) = l;
}

// ---------------- kernel 4: flash attention ----------------
// block: one (bh, 128-q-tile); 4 waves x 32 q-rows. KV tiles of 64, double-buffered.
// Swapped QK^T: S^T[kv][q] = mfma(A=K, B=Q): lane&31 = q column -> softmax lane-local.
// LDS layout (bytes): Kf buf0 [0,8K), Kf buf1 [8K,16K), Vf buf0 [16K,24K), Vf buf1 [24K,32K)
__device__ __forceinline__ void stage_kv(const bf16* Kb, const bf16* VT, bf16* Kf, bf16* Vf,
                                         int bh, int kv0, int buf, int w, int l31, int lh)
{
  #pragma unroll
  for (int qq = 0; qq < 2; ++qq) {
    const int fid = w * 2 + qq, mb = fid >> 2, c = fid & 3;
    const bf16* ks = Kb + ((size_t)bh * SLEN + kv0 + 32 * mb + l31) * HDIM + c * 16 + 8 * lh;
    cp16(ks, Kf + buf * 4096 + fid * 512);
    const bf16* vs = VT + ((size_t)bh * HDIM + 32 * mb + l31) * SLEN + kv0 + c * 16 + 8 * lh;
    cp16(vs, Vf + buf * 4096 + fid * 512);
  }
}

__global__ __launch_bounds__(256, 2) void attn_kernel(
    const bf16* __restrict__ Qb, const bf16* __restrict__ Kb, const bf16* __restrict__ VT,
    const unsigned long long* __restrict__ MB,
    bf16* __restrict__ ctxh, bf16* __restrict__ ctxl)
{
  __shared__ __align__(16) unsigned char smem[32768];
  bf16* Kf = (bf16*)smem;              // [2][4096] elems (8 frags x 512)
  bf16* Vf = (bf16*)(smem + 16384);    // [2][4096]

  const int tid = threadIdx.x, w = tid >> 6, lane = tid & 63, l31 = lane & 31, lh = lane >> 5;
  const int bh = blockIdx.x >> 5, qt = blockIdx.x & 31;
  const int q0 = qt * 128;
  const int qrow = q0 + w * 32 + l31;
  const int lh4 = 4 * lh;

  // Q fragments in registers (B operand: lane&31 = q, k-slot = 16c+8lh+j)
  bf16x8 qf[4];
  {
    const bf16* qp = Qb + ((size_t)bh * SLEN + qrow) * HDIM + 8 * lh;
    #pragma unroll
    for (int c = 0; c < 4; ++c) qf[c] = *(const bf16x8*)(qp + c * 16);
  }

  f32x16 o0, o1;
  #pragma unroll
  for (int r = 0; r < 16; ++r) { o0[r] = 0.f; o1[r] = 0.f; }
  float mrun = -3.0e38f, lsum = 0.f;

  stage_kv(Kb, VT, Kf, Vf, bh, 0, 0, w, l31, lh);
  __syncthreads();

  const int NT = SLEN / 64;
  for (int t = 0; t < NT; ++t) {
    const int cur = t & 1;
    if (t + 1 < NT) stage_kv(Kb, VT, Kf, Vf, bh, (t + 1) * 64, cur ^ 1, w, l31, lh);

    const unsigned long long mw = MB[(size_t)qrow * 64 + t];

    // QK^T: S^T, two 32-kv chunks
    f32x16 s0, s1;
    #pragma unroll
    for (int r = 0; r < 16; ++r) { s0[r] = 0.f; s1[r] = 0.f; }
    #pragma unroll
    for (int c = 0; c < 4; ++c) {
      bf16x8 a0 = *(const bf16x8*)(Kf + cur * 4096 + c * 512 + lane * 8);
      bf16x8 a1 = *(const bf16x8*)(Kf + cur * 4096 + (4 + c) * 512 + lane * 8);
      s0 = mfma32(a0, qf[c], s0);
      s1 = mfma32(a1, qf[c], s1);
    }

    // mask (before scale, like reference), then online softmax (lane-local per q)
    const unsigned wlo = (unsigned)mw, whi = (unsigned)(mw >> 32);
    float p0[16], p1[16];
    float tmax = -3.0e38f;
    #pragma unroll
    for (int r = 0; r < 16; ++r) {
      const int sh = (r & 3) + 8 * (r >> 2) + lh4;  // kv row of this reg (within 32)
      float u0 = ((wlo >> sh) & 1u) ? s0[r] * 0.125f : NEGBIG;
      float u1 = ((whi >> sh) & 1u) ? s1[r] * 0.125f : NEGBIG;
      p0[r] = u0; p1[r] = u1;
      tmax = fmaxf(tmax, fmaxf(u0, u1));
    }
    tmax = fmaxf(tmax, __shfl_xor(tmax, 32));
    const float mnew = fmaxf(mrun, tmax);
    const float alpha = exp2f((mrun - mnew) * LOG2E);
    float psum = 0.f;
    #pragma unroll
    for (int r = 0; r < 16; ++r) {
      float e0 = exp2f((p0[r] - mnew) * LOG2E);
      float e1 = exp2f((p1[r] - mnew) * LOG2E);
      p0[r] = e0; p1[r] = e1; psum += e0 + e1;
    }
    psum += __shfl_xor(psum, 32);
    lsum = lsum * alpha + psum;
    mrun = mnew;
    #pragma unroll
    for (int r = 0; r < 16; ++r) { o0[r] *= alpha; o1[r] *= alpha; }

    // pack P into PV B-fragments via explicit half-exchange (__shfl_xor 32):
    // bp[C] element j (lane half lh) must be P[kv = 16*C + 8*lh + j][q = l31].
    // own regs r'=0..3 -> kv' = r' + 4*lh; r'=4..7 -> kv' = 8 + (r'-4) + 4*lh.
    bf16x8 bp[4];
    #pragma unroll
    for (int mi = 0; mi < 2; ++mi) {
      #pragma unroll
      for (int cc = 0; cc < 2; ++cc) {
        const int rb = cc * 8;
        float v0_ = (mi ? p1[rb + 0] : p0[rb + 0]);
        float v1_ = (mi ? p1[rb + 1] : p0[rb + 1]);
        float v2_ = (mi ? p1[rb + 2] : p0[rb + 2]);
        float v3_ = (mi ? p1[rb + 3] : p0[rb + 3]);
        float v4_ = (mi ? p1[rb + 4] : p0[rb + 4]);
        float v5_ = (mi ? p1[rb + 5] : p0[rb + 5]);
        float v6_ = (mi ? p1[rb + 6] : p0[rb + 6]);
        float v7_ = (mi ? p1[rb + 7] : p0[rb + 7]);
        unsigned wA0 = pk2(v0_, v1_), wA1 = pk2(v2_, v3_);
        unsigned wB0 = pk2(v4_, v5_), wB1 = pk2(v6_, v7_);
        unsigned xA0 = __shfl_xor(wA0, 32);
        unsigned xA1 = __shfl_xor(wA1, 32);
        unsigned xB0 = __shfl_xor(wB0, 32);
        unsigned xB1 = __shfl_xor(wB1, 32);
        uint4v fw;
        fw[0] = lh ? xB0 : wA0;   // j0,1: kv 16C+8lh+{0,1}
        fw[1] = lh ? xB1 : wA1;   // j2,3
        fw[2] = lh ? wB0 : xA0;   // j4,5
        fw[3] = lh ? wB1 : xA1;   // j6,7
        bp[2 * mi + cc] = __builtin_bit_cast(bf16x8, fw);
      }
    }

    // PV: ctx^T[d][q] += V^T x P^T (A=V^T frag from LDS, same k-slot map as bp)
    #pragma unroll
    for (int c = 0; c < 4; ++c) {
      bf16x8 v0 = *(const bf16x8*)(Vf + cur * 4096 + c * 512 + lane * 8);
      bf16x8 v1 = *(const bf16x8*)(Vf + cur * 4096 + (4 + c) * 512 + lane * 8);
      o0 = mfma32(v0, bp[c], o0);
      o1 = mfma32(v1, bp[c], o1);
    }

    __syncthreads();  // drains vmcnt(0): next tile staged & all reads of this buffer done
  }

  // epilogue: normalize, split hi/lo, transpose via LDS, write ctx [BH][S][64]
  const float inv = 1.f / lsum;
  #pragma unroll
  for (int r = 0; r < 16; ++r) { o0[r] *= inv; o1[r] *= inv; }

  bf16* Tr = (bf16*)smem;  // [128][72] bf16 (padded stride)
  const int rloc = tid >> 1, half = tid & 1;

  // hi plane
  #pragma unroll
  for (int r = 0; r < 16; ++r) {
    const int dr = (r & 3) + 8 * (r >> 2) + lh4;
    Tr[(w * 32 + l31) * 72 + dr]      = (bf16)o0[r];
    Tr[(w * 32 + l31) * 72 + 32 + dr] = (bf16)o1[r];
  }
  __syncthreads();
  {
    bf16* dst = ctxh + ((size_t)bh * SLEN + q0 + rloc) * 64 + half * 32;
    const bf16* srcp = Tr + rloc * 72 + half * 32;
    #pragma unroll
    for (int u = 0; u < 4; ++u) *(uint4v*)(dst + u * 8) = *(const uint4v*)(srcp + u * 8);
  }
  __syncthreads();
  // lo plane
  #pragma unroll
  for (int r = 0; r < 16; ++r) {
    const int dr = (r & 3) + 8 * (r >> 2) + lh4;
    const float h0 = (float)(bf16)o0[r];
    const float h1 = (float)(bf16)o1[r];
    Tr[(w * 32 + l31) * 72 + dr]      = (bf16)(o0[r] - h0);
    Tr[(w * 32 + l31) * 72 + 32 + dr] = (bf16)(o1[r] - h1);
  }
  __syncthreads();
  {
    bf16* dst = ctxl + ((size_t)bh * SLEN + q0 + rloc) * 64 + half * 32;
    const bf16* srcp = Tr + rloc * 72 + half * 32;
    #pragma unroll
    for (int u = 0; u < 4; ++u) *(uint4v*)(dst + u * 8) = *(const uint4v*)(srcp + u * 8);
  }
}

// ---------------- kernel 5: output projection (hi/lo split GEMM) ----------------
// out[bs][e] = sum_k concat[bs][k] * Wo[e][k] + bo[e], k = h*64+d; ctx stored [B][H][S][64].
__global__ __launch_bounds__(256, 2) void out_proj(
    const bf16* __restrict__ CH, const bf16* __restrict__ CL,
    const bf16* __restrict__ WH, const bf16* __restrict__ WL,
    const float* __restrict__ bo, float* __restrict__ out)
{
  __shared__ __align__(16) bf16 Af[2][4][4][64][8];  // [plane][mb][c][lane][8] = 32KB
  const int tid = threadIdx.x, w = tid >> 6, lane = tid & 63, l31 = lane & 31, lh = lane >> 5;
  const int mt = blockIdx.x >> 3, nt = blockIdx.x & 7;
  const int bs0 = mt * 128, n0 = nt * 64;
  const int b = bs0 >> 12, sbase = bs0 & 4095;

  f32x16 a0, a1;
  #pragma unroll
  for (int r = 0; r < 16; ++r) { a0[r] = 0.f; a1[r] = 0.f; }

  for (int kk = 0; kk < 8; ++kk) {  // K-step = one head's 64 dims
    __syncthreads();
    #pragma unroll
    for (int qq = 0; qq < 8; ++qq) {
      const int fid = w * 8 + qq, pl = fid >> 4, mb = (fid >> 2) & 3, c = fid & 3;
      const bf16* src = (pl ? CL : CH) +
          ((size_t)(b * 8 + kk) * SLEN + sbase + 32 * mb + l31) * 64 + 16 * c + 8 * lh;
      cp16(src, &Af[pl][mb][c][0][0]);
    }
    __syncthreads();  // implicit vmcnt(0) drain before barrier

    bf16x8 bh0[4], bl0[4], bh1[4], bl1[4], ah[4], al[4];
    #pragma unroll
    for (int c = 0; c < 4; ++c) {
      const size_t o0off = (size_t)(n0 + l31) * EMB + kk * 64 + 16 * c + 8 * lh;
      const size_t o1off = (size_t)(n0 + l31 + 32) * EMB + kk * 64 + 16 * c + 8 * lh;
      bh0[c] = *(const bf16x8*)(WH + o0off);
      bl0[c] = *(const bf16x8*)(WL + o0off);
      bh1[c] = *(const bf16x8*)(WH + o1off);
      bl1[c] = *(const bf16x8*)(WL + o1off);
      ah[c] = *(const bf16x8*)(&Af[0][w][c][lane][0]);
      al[c] = *(const bf16x8*)(&Af[1][w][c][lane][0]);
    }
    #pragma unroll
    for (int c = 0; c < 4; ++c) {
      a0 = mfma32(ah[c], bh0[c], a0);
      a0 = mfma32(ah[c], bl0[c], a0);
      a0 = mfma32(al[c], bh0[c], a0);
      a1 = mfma32(ah[c], bh1[c], a1);
      a1 = mfma32(ah[c], bl1[c], a1);
      a1 = mfma32(al[c], bh1[c], a1);
    }
  }

  const float bv0 = bo[n0 + l31], bv1 = bo[n0 + l31 + 32];
  #pragma unroll
  for (int r = 0; r < 16; ++r) {
    const int row = bs0 + w * 32 + (r & 3) + 8 * (r >> 2) + 4 * lh;
    out[(size_t)row * EMB + n0 + l31]      = a0[r] + bv0;
    out[(size_t)row * EMB + n0 + l31 + 32] = a1[r] + bv1;
  }
}

// ---------------- launch ----------------
extern "C" void kernel_launch(void* const* d_in, const int* in_sizes, int n_in,
                              void* d_out, int out_size, void* d_ws, size_t ws_size,
                              hipStream_t stream)
{
  (void)in_sizes; (void)n_in; (void)out_size; (void)ws_size;
  const float* key   = (const float*)d_in[0];
  const float* query = (const float*)d_in[1];
  const float* value = (const float*)d_in[2];
  const int*   mask  = (const int*)d_in[3];
  const float* Wq    = (const float*)d_in[4];
  const float* Wk    = (const float*)d_in[5];
  const float* Wv    = (const float*)d_in[6];
  const float* Wo    = (const float*)d_in[7];
  const float* bo    = (const float*)d_in[8];
  float* out = (float*)d_out;

  char* ws = (char*)d_ws;                       // ~43.5 MB used
  bf16* Qb = (bf16*)(ws);                       // 8 MB  [BH][S][64]
  bf16* Kb = (bf16*)(ws + (8ull  << 20));       // 8 MB  [BH][S][64]
  bf16* VT = (bf16*)(ws + (16ull << 20));       // 8 MB  [BH][64][S]
  unsigned long long* MBp = (unsigned long long*)(ws + (24ull << 20));  // 2 MB
  bf16* CH = (bf16*)(ws + (26ull << 20));       // 8 MB  ctx hi
  bf16* CL = (bf16*)(ws + (34ull << 20));       // 8 MB  ctx lo
  bf16* WH = (bf16*)(ws + (42ull << 20));       // 512 KB
  bf16* WL = (bf16*)(ws + (42ull << 20) + (512ull << 10));

  proj_qkv<<<512, 256, 0, stream>>>(key, query, value, Wq, Wk, Wv, Qb, Kb, VT);
  pack_mask<<<1024, 256, 0, stream>>>(mask, MBp);
  wo_split<<<256, 256, 0, stream>>>(Wo, WH, WL);
  attn_kernel<<<512, 256, 0, stream>>>(Qb, Kb, VT, MBp, CH, CL);
  out_proj<<<512, 256, 0, stream>>>(CH, CL, WH, WL, bo, out);
}

// Round 3
// 275.476 us; speedup vs baseline: 1.0547x; 1.0547x over previous
//
#include <hip/hip_runtime.h>

// ---------------- types / helpers ----------------
typedef __bf16 bf16;
typedef __attribute__((ext_vector_type(8)))  bf16     bf16x8;
typedef __attribute__((ext_vector_type(4)))  bf16     bf16x4;
typedef __attribute__((ext_vector_type(16))) float    f32x16;
typedef __attribute__((ext_vector_type(4)))  float    f32x4;
typedef __attribute__((ext_vector_type(4)))  unsigned uint4v;
typedef __attribute__((ext_vector_type(2)))  unsigned uint2v;

#define SLEN 4096
#define NHEAD 8
#define HDIM 64
#define EMB 512
#define LOG2E 1.4426950408889634f
#define SCALE_LOG2E 0.1803336100254854f  /* 0.125 * log2(e) */

__device__ __forceinline__ f32x16 mfma32(bf16x8 a, bf16x8 b, f32x16 c) {
  return __builtin_amdgcn_mfma_f32_32x32x16_bf16(a, b, c, 0, 0, 0);
}

// async global->LDS, 16B per lane; LDS dest is wave-uniform base + lane*16
__device__ __forceinline__ void cp16(const void* g, const void* l) {
  __builtin_amdgcn_global_load_lds(
      (__attribute__((address_space(1))) unsigned int*)(unsigned long long)g,
      (__attribute__((address_space(3))) unsigned int*)(unsigned int)(unsigned long long)l,
      16, 0, 0);
}

__device__ __forceinline__ unsigned pk2(float a, float b) {
  unsigned short ua = __builtin_bit_cast(unsigned short, (bf16)a);
  unsigned short ub = __builtin_bit_cast(unsigned short, (bf16)b);
  return (unsigned)ua | ((unsigned)ub << 16);
}

// ---------------- kernel 1: QKV projections (MFMA) ----------------
__global__ __launch_bounds__(256, 2) void proj_qkv(
    const float* __restrict__ key, const float* __restrict__ query, const float* __restrict__ value,
    const float* __restrict__ Wq, const float* __restrict__ Wk, const float* __restrict__ Wv,
    bf16* __restrict__ Qb, bf16* __restrict__ Kb, bf16* __restrict__ VT)
{
  __shared__ __align__(16) bf16 tile[128][64];
  const int tid = threadIdx.x, w = tid >> 6, lane = tid & 63, l31 = lane & 31, lh = lane >> 5;
  const int r0 = blockIdx.x * 128;
  const int m0 = r0 + w * 32;

  #pragma unroll
  for (int p = 0; p < 3; ++p) {
    const float* X = (p == 0) ? query : (p == 1) ? key : value;
    const float* W = (p == 0) ? Wq    : (p == 1) ? Wk  : Wv;

    bf16x8 af[4];
    {
      const float* xr = X + (size_t)(m0 + l31) * 64 + 8 * lh;
      #pragma unroll
      for (int c = 0; c < 4; ++c) {
        f32x4 lo = *(const f32x4*)(xr + c * 16);
        f32x4 hi = *(const f32x4*)(xr + c * 16 + 4);
        bf16x8 v;
        #pragma unroll
        for (int j = 0; j < 4; ++j) { v[j] = (bf16)lo[j]; v[4 + j] = (bf16)hi[j]; }
        af[c] = v;
      }
    }
    bf16x8 bfr[2][4];
    #pragma unroll
    for (int nb = 0; nb < 2; ++nb) {
      const float* wr = W + (size_t)(l31 + 32 * nb) * 64 + 8 * lh;
      #pragma unroll
      for (int c = 0; c < 4; ++c) {
        f32x4 lo = *(const f32x4*)(wr + c * 16);
        f32x4 hi = *(const f32x4*)(wr + c * 16 + 4);
        bf16x8 v;
        #pragma unroll
        for (int j = 0; j < 4; ++j) { v[j] = (bf16)lo[j]; v[4 + j] = (bf16)hi[j]; }
        bfr[nb][c] = v;
      }
    }
    f32x16 a0, a1;
    #pragma unroll
    for (int r = 0; r < 16; ++r) { a0[r] = 0.f; a1[r] = 0.f; }
    #pragma unroll
    for (int c = 0; c < 4; ++c) {
      a0 = mfma32(af[c], bfr[0][c], a0);
      a1 = mfma32(af[c], bfr[1][c], a1);
    }

    __syncthreads();
    #pragma unroll
    for (int r = 0; r < 16; ++r) {
      const int row = w * 32 + (r & 3) + 8 * (r >> 2) + 4 * lh;
      tile[row][l31]      = (bf16)a0[r];
      tile[row][l31 + 32] = (bf16)a1[r];
    }
    __syncthreads();

    if (p < 2) {
      bf16* OUT = p ? Kb : Qb;
      const int rloc = tid >> 1, half = tid & 1;
      const int rg = r0 + rloc, bs = rg >> 3, h = rg & 7, b = bs >> 12, sidx = bs & 4095;
      bf16* dst = OUT + (((size_t)(b * 8 + h) * SLEN + sidx) * 64 + half * 32);
      const bf16* srcp = &tile[rloc][half * 32];
      #pragma unroll
      for (int u = 0; u < 4; ++u) *(uint4v*)(dst + u * 8) = *(const uint4v*)(srcp + u * 8);
    } else {
      const int h = tid >> 5, d0 = tid & 31;
      const int b = blockIdx.x >> 8, s0 = (blockIdx.x * 16) & 4095;
      #pragma unroll
      for (int dh = 0; dh < 2; ++dh) {
        const int dd = d0 + 32 * dh;
        unsigned pk4[8];
        #pragma unroll
        for (int t2 = 0; t2 < 8; ++t2) {
          unsigned short ua = __builtin_bit_cast(unsigned short, tile[(2 * t2) * 8 + h][dd]);
          unsigned short ub = __builtin_bit_cast(unsigned short, tile[(2 * t2 + 1) * 8 + h][dd]);
          pk4[t2] = (unsigned)ua | ((unsigned)ub << 16);
        }
        bf16* dst = VT + ((size_t)(b * 8 + h) * 64 + dd) * SLEN + s0;
        uint4v A; A[0] = pk4[0]; A[1] = pk4[1]; A[2] = pk4[2]; A[3] = pk4[3];
        uint4v Bv; Bv[0] = pk4[4]; Bv[1] = pk4[5]; Bv[2] = pk4[6]; Bv[3] = pk4[7];
        *(uint4v*)(dst) = A;
        *(uint4v*)(dst + 8) = Bv;
      }
    }
  }
}

// ---------------- kernel 2: mask -> bitmask, TRANSPOSED [word][q] ----------------
// MBt[wi*SLEN + q] bit l = (mask[q][wi*64+l] != 0)
__global__ void pack_mask(const int* __restrict__ mask, unsigned long long* __restrict__ MBt)
{
  const int w = threadIdx.x >> 6, lane = threadIdx.x & 63;
  const int q = blockIdx.x * 4 + w;
  const int* row = mask + (size_t)q * SLEN;
  unsigned long long mine = 0ull;
  #pragma unroll 4
  for (int i = 0; i < 64; ++i) {
    unsigned long long b = __ballot(row[i * 64 + lane] != 0);
    if (i == lane) mine = b;
  }
  MBt[(size_t)lane * SLEN + q] = mine;
}

// ---------------- kernel 3: Wo -> hi/lo bf16 planes ----------------
__global__ void wo_split(const float* __restrict__ Wo, bf16* __restrict__ WH, bf16* __restrict__ WL)
{
  const int i = (blockIdx.x * 256 + threadIdx.x) * 4;
  f32x4 v = *(const f32x4*)(Wo + i);
  bf16x4 h, l;
  #pragma unroll
  for (int j = 0; j < 4; ++j) { h[j] = (bf16)v[j]; l[j] = (bf16)(v[j] - (float)h[j]); }
  *(bf16x4*)(WH + i) = h;
  *(bf16x4*)(WL + i) = l;
}

// ---------------- kernel 4: flash attention (no-max softmax, QBLK=64, 2 waves) ----------------
// LDS: Kf buf0 [0,8K), buf1 [8K,16K); Vf buf0 [16K,24K), buf1 [24K,32K)
__device__ __forceinline__ void stage_kv2(const bf16* Kb, const bf16* VT, bf16* Kf, bf16* Vf,
                                          int bh, int kv0, int buf, int w, int l31, int lh)
{
  #pragma unroll
  for (int qq = 0; qq < 4; ++qq) {
    const int fid = w * 4 + qq, mb = fid >> 2, c = fid & 3;
    const bf16* ks = Kb + ((size_t)bh * SLEN + kv0 + 32 * mb + l31) * HDIM + c * 16 + 8 * lh;
    cp16(ks, Kf + buf * 4096 + fid * 512);
    const bf16* vs = VT + ((size_t)bh * HDIM + 32 * mb + l31) * SLEN + kv0 + c * 16 + 8 * lh;
    cp16(vs, Vf + buf * 4096 + fid * 512);
  }
}

__global__ __launch_bounds__(128, 2) void attn_kernel(
    const bf16* __restrict__ Qb, const bf16* __restrict__ Kb, const bf16* __restrict__ VT,
    const unsigned long long* __restrict__ MBt,
    bf16* __restrict__ ctxh, bf16* __restrict__ ctxl)
{
  __shared__ __align__(16) unsigned char smem[32768];
  bf16* Kf = (bf16*)smem;              // [2][4096] elems
  bf16* Vf = (bf16*)(smem + 16384);    // [2][4096]

  const int tid = threadIdx.x, w = tid >> 6, lane = tid & 63, l31 = lane & 31, lh = lane >> 5;
  const int bh = blockIdx.x >> 6, qt = blockIdx.x & 63;
  const int q0 = qt * 64;
  const int qrow = q0 + w * 32 + l31;
  const int lh4 = 4 * lh;

  // Q fragments (B operand: lane&31 = q, k-slot = 16c+8lh+j)
  bf16x8 qf[4];
  {
    const bf16* qp = Qb + ((size_t)bh * SLEN + qrow) * HDIM + 8 * lh;
    #pragma unroll
    for (int c = 0; c < 4; ++c) qf[c] = *(const bf16x8*)(qp + c * 16);
  }

  f32x16 o0, o1;
  #pragma unroll
  for (int r = 0; r < 16; ++r) { o0[r] = 0.f; o1[r] = 0.f; }
  float ls0 = 0.f, ls1 = 0.f, ls2 = 0.f, ls3 = 0.f;

  stage_kv2(Kb, VT, Kf, Vf, bh, 0, 0, w, l31, lh);
  __syncthreads();

  unsigned long long mw = MBt[qrow];  // tile 0, coalesced [word][q] layout
  const int NT = SLEN / 64;
  for (int t = 0; t < NT; ++t) {
    const int cur = t & 1;
    if (t + 1 < NT) stage_kv2(Kb, VT, Kf, Vf, bh, (t + 1) * 64, cur ^ 1, w, l31, lh);
    unsigned long long mwn = 0ull;
    if (t + 1 < NT) mwn = MBt[(size_t)(t + 1) * SLEN + qrow];

    // QK^T: S^T, two 32-kv chunks
    f32x16 s0, s1;
    #pragma unroll
    for (int r = 0; r < 16; ++r) { s0[r] = 0.f; s1[r] = 0.f; }
    #pragma unroll
    for (int c = 0; c < 4; ++c) {
      bf16x8 a0 = *(const bf16x8*)(Kf + cur * 4096 + c * 512 + lane * 8);
      bf16x8 a1 = *(const bf16x8*)(Kf + cur * 4096 + (4 + c) * 512 + lane * 8);
      s0 = mfma32(a0, qf[c], s0);
      s1 = mfma32(a1, qf[c], s1);
    }

    // no-max softmax: e = exp2(s*0.125*log2e) * maskbit (exact vs reference:
    // softmax is shift-invariant; masked -1e20 terms become exact 0)
    const unsigned wlo = (unsigned)mw, whi = (unsigned)(mw >> 32);
    float p0[16], p1[16];
    #pragma unroll
    for (int r = 0; r < 16; ++r) {
      const int sh = (r & 3) + 8 * (r >> 2) + lh4;  // kv row within 32-chunk
      float e0 = exp2f(s0[r] * SCALE_LOG2E);
      float e1 = exp2f(s1[r] * SCALE_LOG2E);
      e0 *= (float)((wlo >> sh) & 1u);
      e1 *= (float)((whi >> sh) & 1u);
      p0[r] = e0; p1[r] = e1;
      if ((r & 1) == 0) { ls0 += e0; ls1 += e1; } else { ls2 += e0; ls3 += e1; }
    }

    // pack P into PV B-fragments via permlane32_swap (verified == shfl_xor(32) map)
    bf16x8 bp[4];
    #pragma unroll
    for (int mi = 0; mi < 2; ++mi) {
      #pragma unroll
      for (int cc = 0; cc < 2; ++cc) {
        const int rb = cc * 8;
        unsigned wA0 = pk2(mi ? p1[rb + 0] : p0[rb + 0], mi ? p1[rb + 1] : p0[rb + 1]);
        unsigned wA1 = pk2(mi ? p1[rb + 2] : p0[rb + 2], mi ? p1[rb + 3] : p0[rb + 3]);
        unsigned wB0 = pk2(mi ? p1[rb + 4] : p0[rb + 4], mi ? p1[rb + 5] : p0[rb + 5]);
        unsigned wB1 = pk2(mi ? p1[rb + 6] : p0[rb + 6], mi ? p1[rb + 7] : p0[rb + 7]);
        uint2v r0 = __builtin_amdgcn_permlane32_swap(wA0, wB0, false, false);
        uint2v r1 = __builtin_amdgcn_permlane32_swap(wA1, wB1, false, false);
        uint4v fw; fw[0] = r0[0]; fw[1] = r1[0]; fw[2] = r0[1]; fw[3] = r1[1];
        bp[2 * mi + cc] = __builtin_bit_cast(bf16x8, fw);
      }
    }

    // PV: ctx^T[d][q] += V^T x P^T
    #pragma unroll
    for (int c = 0; c < 4; ++c) {
      bf16x8 v0 = *(const bf16x8*)(Vf + cur * 4096 + c * 512 + lane * 8);
      bf16x8 v1 = *(const bf16x8*)(Vf + cur * 4096 + (4 + c) * 512 + lane * 8);
      o0 = mfma32(v0, bp[c], o0);
      o1 = mfma32(v1, bp[c], o1);
    }

    __syncthreads();
    mw = mwn;
  }

  // epilogue: reduce lsum across halves (once), normalize, hi/lo, transpose, write
  float lsum = (ls0 + ls2) + (ls1 + ls3);
  lsum += __shfl_xor(lsum, 32);
  const float inv = 1.f / lsum;
  #pragma unroll
  for (int r = 0; r < 16; ++r) { o0[r] *= inv; o1[r] *= inv; }

  bf16* Tr = (bf16*)smem;  // [64][72] bf16 (padded stride)
  const int rloc = tid >> 1, half = tid & 1;

  #pragma unroll
  for (int r = 0; r < 16; ++r) {
    const int dr = (r & 3) + 8 * (r >> 2) + lh4;
    Tr[(w * 32 + l31) * 72 + dr]      = (bf16)o0[r];
    Tr[(w * 32 + l31) * 72 + 32 + dr] = (bf16)o1[r];
  }
  __syncthreads();
  {
    bf16* dst = ctxh + ((size_t)bh * SLEN + q0 + rloc) * 64 + half * 32;
    const bf16* srcp = Tr + rloc * 72 + half * 32;
    #pragma unroll
    for (int u = 0; u < 4; ++u) *(uint4v*)(dst + u * 8) = *(const uint4v*)(srcp + u * 8);
  }
  __syncthreads();
  #pragma unroll
  for (int r = 0; r < 16; ++r) {
    const int dr = (r & 3) + 8 * (r >> 2) + lh4;
    const float h0 = (float)(bf16)o0[r];
    const float h1 = (float)(bf16)o1[r];
    Tr[(w * 32 + l31) * 72 + dr]      = (bf16)(o0[r] - h0);
    Tr[(w * 32 + l31) * 72 + 32 + dr] = (bf16)(o1[r] - h1);
  }
  __syncthreads();
  {
    bf16* dst = ctxl + ((size_t)bh * SLEN + q0 + rloc) * 64 + half * 32;
    const bf16* srcp = Tr + rloc * 72 + half * 32;
    #pragma unroll
    for (int u = 0; u < 4; ++u) *(uint4v*)(dst + u * 8) = *(const uint4v*)(srcp + u * 8);
  }
}

// ---------------- kernel 5: output projection (hi/lo split GEMM) ----------------
__global__ __launch_bounds__(256, 2) void out_proj(
    const bf16* __restrict__ CH, const bf16* __restrict__ CL,
    const bf16* __restrict__ WH, const bf16* __restrict__ WL,
    const float* __restrict__ bo, float* __restrict__ out)
{
  __shared__ __align__(16) bf16 Af[2][4][4][64][8];  // 32KB
  const int tid = threadIdx.x, w = tid >> 6, lane = tid & 63, l31 = lane & 31, lh = lane >> 5;
  const int mt = blockIdx.x >> 3, nt = blockIdx.x & 7;
  const int bs0 = mt * 128, n0 = nt * 64;
  const int b = bs0 >> 12, sbase = bs0 & 4095;

  f32x16 a0, a1;
  #pragma unroll
  for (int r = 0; r < 16; ++r) { a0[r] = 0.f; a1[r] = 0.f; }

  for (int kk = 0; kk < 8; ++kk) {
    __syncthreads();
    #pragma unroll
    for (int qq = 0; qq < 8; ++qq) {
      const int fid = w * 8 + qq, pl = fid >> 4, mb = (fid >> 2) & 3, c = fid & 3;
      const bf16* src = (pl ? CL : CH) +
          ((size_t)(b * 8 + kk) * SLEN + sbase + 32 * mb + l31) * 64 + 16 * c + 8 * lh;
      cp16(src, &Af[pl][mb][c][0][0]);
    }
    __syncthreads();

    bf16x8 bh0[4], bl0[4], bh1[4], bl1[4], ah[4], al[4];
    #pragma unroll
    for (int c = 0; c < 4; ++c) {
      const size_t o0off = (size_t)(n0 + l31) * EMB + kk * 64 + 16 * c + 8 * lh;
      const size_t o1off = (size_t)(n0 + l31 + 32) * EMB + kk * 64 + 16 * c + 8 * lh;
      bh0[c] = *(const bf16x8*)(WH + o0off);
      bl0[c] = *(const bf16x8*)(WL + o0off);
      bh1[c] = *(const bf16x8*)(WH + o1off);
      bl1[c] = *(const bf16x8*)(WL + o1off);
      ah[c] = *(const bf16x8*)(&Af[0][w][c][lane][0]);
      al[c] = *(const bf16x8*)(&Af[1][w][c][lane][0]);
    }
    #pragma unroll
    for (int c = 0; c < 4; ++c) {
      a0 = mfma32(ah[c], bh0[c], a0);
      a0 = mfma32(ah[c], bl0[c], a0);
      a0 = mfma32(al[c], bh0[c], a0);
      a1 = mfma32(ah[c], bh1[c], a1);
      a1 = mfma32(ah[c], bl1[c], a1);
      a1 = mfma32(al[c], bh1[c], a1);
    }
  }

  const float bv0 = bo[n0 + l31], bv1 = bo[n0 + l31 + 32];
  #pragma unroll
  for (int r = 0; r < 16; ++r) {
    const int row = bs0 + w * 32 + (r & 3) + 8 * (r >> 2) + 4 * lh;
    out[(size_t)row * EMB + n0 + l31]      = a0[r] + bv0;
    out[(size_t)row * EMB + n0 + l31 + 32] = a1[r] + bv1;
  }
}

// ---------------- launch ----------------
extern "C" void kernel_launch(void* const* d_in, const int* in_sizes, int n_in,
                              void* d_out, int out_size, void* d_ws, size_t ws_size,
                              hipStream_t stream)
{
  (void)in_sizes; (void)n_in; (void)out_size; (void)ws_size;
  const float* key   = (const float*)d_in[0];
  const float* query = (const float*)d_in[1];
  const float* value = (const float*)d_in[2];
  const int*   mask  = (const int*)d_in[3];
  const float* Wq    = (const float*)d_in[4];
  const float* Wk    = (const float*)d_in[5];
  const float* Wv    = (const float*)d_in[6];
  const float* Wo    = (const float*)d_in[7];
  const float* bo    = (const float*)d_in[8];
  float* out = (float*)d_out;

  char* ws = (char*)d_ws;                       // ~43.5 MB used
  bf16* Qb = (bf16*)(ws);                       // 8 MB  [BH][S][64]
  bf16* Kb = (bf16*)(ws + (8ull  << 20));       // 8 MB  [BH][S][64]
  bf16* VT = (bf16*)(ws + (16ull << 20));       // 8 MB  [BH][64][S]
  unsigned long long* MBp = (unsigned long long*)(ws + (24ull << 20));  // 2 MB [word][q]
  bf16* CH = (bf16*)(ws + (26ull << 20));       // 8 MB  ctx hi
  bf16* CL = (bf16*)(ws + (34ull << 20));       // 8 MB  ctx lo
  bf16* WH = (bf16*)(ws + (42ull << 20));       // 512 KB
  bf16* WL = (bf16*)(ws + (42ull << 20) + (512ull << 10));

  proj_qkv<<<512, 256, 0, stream>>>(key, query, value, Wq, Wk, Wv, Qb, Kb, VT);
  pack_mask<<<1024, 256, 0, stream>>>(mask, MBp);
  wo_split<<<256, 256, 0, stream>>>(Wo, WH, WL);
  attn_kernel<<<1024, 128, 0, stream>>>(Qb, Kb, VT, MBp, CH, CL);
  out_proj<<<512, 256, 0, stream>>>(CH, CL, WH, WL, bo, out);
}

// Round 4
// 233.774 us; speedup vs baseline: 1.2428x; 1.1784x over previous
//
#include <hip/hip_runtime.h>

// ---------------- types / helpers ----------------
typedef __bf16 bf16;
typedef __attribute__((ext_vector_type(8)))  bf16     bf16x8;
typedef __attribute__((ext_vector_type(4)))  bf16     bf16x4;
typedef __attribute__((ext_vector_type(16))) float    f32x16;
typedef __attribute__((ext_vector_type(4)))  float    f32x4;
typedef __attribute__((ext_vector_type(4)))  unsigned uint4v;
typedef __attribute__((ext_vector_type(2)))  unsigned uint2v;

#define SLEN 4096
#define NHEAD 8
#define HDIM 64
#define EMB 512
#define NTILES 64            /* SLEN/64 kv tiles */
#define SCALE_LOG2E 0.1803336100254854f  /* 0.125 * log2(e) */

__device__ __forceinline__ f32x16 mfma32(bf16x8 a, bf16x8 b, f32x16 c) {
  return __builtin_amdgcn_mfma_f32_32x32x16_bf16(a, b, c, 0, 0, 0);
}

// async global->LDS, 16B per lane; LDS dest is wave-uniform base + lane*16
__device__ __forceinline__ void cp16(const void* g, const void* l) {
  __builtin_amdgcn_global_load_lds(
      (__attribute__((address_space(1))) unsigned int*)(unsigned long long)g,
      (__attribute__((address_space(3))) unsigned int*)(unsigned int)(unsigned long long)l,
      16, 0, 0);
}

__device__ __forceinline__ unsigned pk2(float a, float b) {
  unsigned short ua = __builtin_bit_cast(unsigned short, (bf16)a);
  unsigned short ub = __builtin_bit_cast(unsigned short, (bf16)b);
  return (unsigned)ua | ((unsigned)ub << 16);
}

// ---------------- kernel 1: QKV projections (MFMA) ----------------
__global__ __launch_bounds__(256, 2) void proj_qkv(
    const float* __restrict__ key, const float* __restrict__ query, const float* __restrict__ value,
    const float* __restrict__ Wq, const float* __restrict__ Wk, const float* __restrict__ Wv,
    bf16* __restrict__ Qb, bf16* __restrict__ Kb, bf16* __restrict__ VT)
{
  __shared__ __align__(16) bf16 tile[128][64];
  const int tid = threadIdx.x, w = tid >> 6, lane = tid & 63, l31 = lane & 31, lh = lane >> 5;
  const int r0 = blockIdx.x * 128;
  const int m0 = r0 + w * 32;

  #pragma unroll
  for (int p = 0; p < 3; ++p) {
    const float* X = (p == 0) ? query : (p == 1) ? key : value;
    const float* W = (p == 0) ? Wq    : (p == 1) ? Wk  : Wv;

    bf16x8 af[4];
    {
      const float* xr = X + (size_t)(m0 + l31) * 64 + 8 * lh;
      #pragma unroll
      for (int c = 0; c < 4; ++c) {
        f32x4 lo = *(const f32x4*)(xr + c * 16);
        f32x4 hi = *(const f32x4*)(xr + c * 16 + 4);
        bf16x8 v;
        #pragma unroll
        for (int j = 0; j < 4; ++j) { v[j] = (bf16)lo[j]; v[4 + j] = (bf16)hi[j]; }
        af[c] = v;
      }
    }
    bf16x8 bfr[2][4];
    #pragma unroll
    for (int nb = 0; nb < 2; ++nb) {
      const float* wr = W + (size_t)(l31 + 32 * nb) * 64 + 8 * lh;
      #pragma unroll
      for (int c = 0; c < 4; ++c) {
        f32x4 lo = *(const f32x4*)(wr + c * 16);
        f32x4 hi = *(const f32x4*)(wr + c * 16 + 4);
        bf16x8 v;
        #pragma unroll
        for (int j = 0; j < 4; ++j) { v[j] = (bf16)lo[j]; v[4 + j] = (bf16)hi[j]; }
        bfr[nb][c] = v;
      }
    }
    f32x16 a0, a1;
    #pragma unroll
    for (int r = 0; r < 16; ++r) { a0[r] = 0.f; a1[r] = 0.f; }
    #pragma unroll
    for (int c = 0; c < 4; ++c) {
      a0 = mfma32(af[c], bfr[0][c], a0);
      a1 = mfma32(af[c], bfr[1][c], a1);
    }

    __syncthreads();
    #pragma unroll
    for (int r = 0; r < 16; ++r) {
      const int row = w * 32 + (r & 3) + 8 * (r >> 2) + 4 * lh;
      tile[row][l31]      = (bf16)a0[r];
      tile[row][l31 + 32] = (bf16)a1[r];
    }
    __syncthreads();

    if (p < 2) {
      bf16* OUT = p ? Kb : Qb;
      const int rloc = tid >> 1, half = tid & 1;
      const int rg = r0 + rloc, bs = rg >> 3, h = rg & 7, b = bs >> 12, sidx = bs & 4095;
      bf16* dst = OUT + (((size_t)(b * 8 + h) * SLEN + sidx) * 64 + half * 32);
      const bf16* srcp = &tile[rloc][half * 32];
      #pragma unroll
      for (int u = 0; u < 4; ++u) *(uint4v*)(dst + u * 8) = *(const uint4v*)(srcp + u * 8);
    } else {
      const int h = tid >> 5, d0 = tid & 31;
      const int b = blockIdx.x >> 8, s0 = (blockIdx.x * 16) & 4095;
      #pragma unroll
      for (int dh = 0; dh < 2; ++dh) {
        const int dd = d0 + 32 * dh;
        unsigned pk4[8];
        #pragma unroll
        for (int t2 = 0; t2 < 8; ++t2) {
          unsigned short ua = __builtin_bit_cast(unsigned short, tile[(2 * t2) * 8 + h][dd]);
          unsigned short ub = __builtin_bit_cast(unsigned short, tile[(2 * t2 + 1) * 8 + h][dd]);
          pk4[t2] = (unsigned)ua | ((unsigned)ub << 16);
        }
        bf16* dst = VT + ((size_t)(b * 8 + h) * 64 + dd) * SLEN + s0;
        uint4v A; A[0] = pk4[0]; A[1] = pk4[1]; A[2] = pk4[2]; A[3] = pk4[3];
        uint4v Bv; Bv[0] = pk4[4]; Bv[1] = pk4[5]; Bv[2] = pk4[6]; Bv[3] = pk4[7];
        *(uint4v*)(dst) = A;
        *(uint4v*)(dst + 8) = Bv;
      }
    }
  }
}

// ---------------- kernel 2: mask -> remapped 32-bit words ----------------
// Output MW[lh][tile][q] : bit (c*16+r) = mask[q][tile*64 + c*32 + (r&3)+8*(r>>2)+4*lh]
// (exactly the bit needed by attn reg r, chunk c, lane-half lh -> const-offset bfe)
__device__ __forceinline__ unsigned nib_compress(unsigned x) {
  // keep nibbles 0,2,4,6 (pre-masked) and pack their 16 bits into low half, order-preserving
  x = (x | (x >> 4)) & 0x00FF00FFu;
  x = (x | (x >> 8)) & 0x0000FFFFu;
  return x;
}
__global__ void pack_mask(const int* __restrict__ mask, unsigned* __restrict__ MW)
{
  const int w = threadIdx.x >> 6, lane = threadIdx.x & 63;
  const int q = blockIdx.x * 4 + w;
  const int* row = mask + (size_t)q * SLEN;
  unsigned long long mine = 0ull;
  #pragma unroll 4
  for (int i = 0; i < 64; ++i) {
    unsigned long long b = __ballot(row[i * 64 + lane] != 0);
    if (i == lane) mine = b;
  }
  const unsigned lo = (unsigned)mine, hi = (unsigned)(mine >> 32);
  const unsigned w0 = nib_compress(lo & 0x0F0F0F0Fu)        | (nib_compress(hi & 0x0F0F0F0Fu) << 16);
  const unsigned w1 = nib_compress((lo >> 4) & 0x0F0F0F0Fu) | (nib_compress((hi >> 4) & 0x0F0F0F0Fu) << 16);
  MW[(size_t)lane * SLEN + q] = w0;                              // lh = 0 plane
  MW[(size_t)NTILES * SLEN + (size_t)lane * SLEN + q] = w1;      // lh = 1 plane
}

// ---------------- kernel 3: Wo -> hi/lo bf16 planes ----------------
__global__ void wo_split(const float* __restrict__ Wo, bf16* __restrict__ WH, bf16* __restrict__ WL)
{
  const int i = (blockIdx.x * 256 + threadIdx.x) * 4;
  f32x4 v = *(const f32x4*)(Wo + i);
  bf16x4 h, l;
  #pragma unroll
  for (int j = 0; j < 4; ++j) { h[j] = (bf16)v[j]; l[j] = (bf16)(v[j] - (float)h[j]); }
  *(bf16x4*)(WH + i) = h;
  *(bf16x4*)(WL + i) = l;
}

// ---------------- kernel 4: flash attention (kv-split, 4 waves, QBLK=64) ----------------
// wave w: q-group (w&1), kv-chunk (w>>1). Max-free softmax => partials are linear;
// kv-chunk partners combine O and lsum in the epilogue via LDS.
// LDS: Kf buf0 [0,8K), buf1 [8K,16K); Vf buf0 [16K,24K), buf1 [24K,32K)
__device__ __forceinline__ void stage_kv4(const bf16* Kb, const bf16* VT, bf16* Kf, bf16* Vf,
                                          int bh, int kv0, int buf, int w, int l31, int lh)
{
  #pragma unroll
  for (int qq = 0; qq < 2; ++qq) {
    const int fid = w * 2 + qq, mb = fid >> 2, c = fid & 3;
    const bf16* ks = Kb + ((size_t)bh * SLEN + kv0 + 32 * mb + l31) * HDIM + c * 16 + 8 * lh;
    cp16(ks, Kf + buf * 4096 + fid * 512);
    const bf16* vs = VT + ((size_t)bh * HDIM + 32 * mb + l31) * SLEN + kv0 + c * 16 + 8 * lh;
    cp16(vs, Vf + buf * 4096 + fid * 512);
  }
}

__global__ __launch_bounds__(256, 4) void attn_kernel(
    const bf16* __restrict__ Qb, const bf16* __restrict__ Kb, const bf16* __restrict__ VT,
    const unsigned* __restrict__ MW,
    bf16* __restrict__ ctxh, bf16* __restrict__ ctxl)
{
  __shared__ __align__(16) unsigned char smem[32768];
  bf16* Kf = (bf16*)smem;              // [2][4096] elems
  bf16* Vf = (bf16*)(smem + 16384);    // [2][4096]

  const int tid = threadIdx.x, w = tid >> 6, lane = tid & 63, l31 = lane & 31, lh = lane >> 5;
  const int qg = w & 1, kc = w >> 1;
  const int bh = blockIdx.x >> 6, qt = blockIdx.x & 63;
  const int q0 = qt * 64;
  const int qrow = q0 + qg * 32 + l31;
  const int lh4 = 4 * lh;

  // Q fragments (B operand: lane&31 = q, k-slot = 16c+8lh+j)
  bf16x8 qf[4];
  {
    const bf16* qp = Qb + ((size_t)bh * SLEN + qrow) * HDIM + 8 * lh;
    #pragma unroll
    for (int c = 0; c < 4; ++c) qf[c] = *(const bf16x8*)(qp + c * 16);
  }

  f32x16 o0, o1;
  #pragma unroll
  for (int r = 0; r < 16; ++r) { o0[r] = 0.f; o1[r] = 0.f; }
  float ls0 = 0.f, ls1 = 0.f, ls2 = 0.f, ls3 = 0.f;

  stage_kv4(Kb, VT, Kf, Vf, bh, 0, 0, w, l31, lh);
  __syncthreads();

  const unsigned* MWl = MW + (size_t)lh * NTILES * SLEN;
  unsigned mw = MWl[qrow];
  for (int t = 0; t < NTILES; ++t) {
    const int cur = t & 1;
    if (t + 1 < NTILES) stage_kv4(Kb, VT, Kf, Vf, bh, (t + 1) * 64, cur ^ 1, w, l31, lh);
    unsigned mwn = 0u;
    if (t + 1 < NTILES) mwn = MWl[(size_t)(t + 1) * SLEN + qrow];

    // QK^T for this wave's 32-kv chunk
    f32x16 s;
    #pragma unroll
    for (int r = 0; r < 16; ++r) s[r] = 0.f;
    #pragma unroll
    for (int c = 0; c < 4; ++c) {
      bf16x8 a = *(const bf16x8*)(Kf + cur * 4096 + (kc * 4 + c) * 512 + lane * 8);
      s = mfma32(a, qf[c], s);
    }

    // max-free softmax: e = exp2(s*0.125*log2e) * maskbit (const-offset bfe)
    const unsigned mwk = mw >> (kc * 16);
    float p[16];
    #pragma unroll
    for (int r = 0; r < 16; ++r) {
      float e = __builtin_amdgcn_exp2f(s[r] * SCALE_LOG2E);
      e *= (float)((mwk >> r) & 1u);
      p[r] = e;
      if      ((r & 3) == 0) ls0 += e;
      else if ((r & 3) == 1) ls1 += e;
      else if ((r & 3) == 2) ls2 += e;
      else                   ls3 += e;
    }

    // pack P into PV B-fragments via permlane32_swap
    bf16x8 bp[2];
    #pragma unroll
    for (int cc = 0; cc < 2; ++cc) {
      const int rb = cc * 8;
      unsigned wA0 = pk2(p[rb + 0], p[rb + 1]);
      unsigned wA1 = pk2(p[rb + 2], p[rb + 3]);
      unsigned wB0 = pk2(p[rb + 4], p[rb + 5]);
      unsigned wB1 = pk2(p[rb + 6], p[rb + 7]);
      uint2v r0 = __builtin_amdgcn_permlane32_swap(wA0, wB0, false, false);
      uint2v r1 = __builtin_amdgcn_permlane32_swap(wA1, wB1, false, false);
      uint4v fw; fw[0] = r0[0]; fw[1] = r1[0]; fw[2] = r0[1]; fw[3] = r1[1];
      bp[cc] = __builtin_bit_cast(bf16x8, fw);
    }

    // PV over this chunk's 32 kv: V frag id = mb*4 + (kc*2+cc)
    #pragma unroll
    for (int cc = 0; cc < 2; ++cc) {
      bf16x8 v0 = *(const bf16x8*)(Vf + cur * 4096 + (0 * 4 + kc * 2 + cc) * 512 + lane * 8);
      bf16x8 v1 = *(const bf16x8*)(Vf + cur * 4096 + (1 * 4 + kc * 2 + cc) * 512 + lane * 8);
      o0 = mfma32(v0, bp[cc], o0);
      o1 = mfma32(v1, bp[cc], o1);
    }

    __syncthreads();
    mw = mwn;
  }

  // ---- epilogue: combine kv-chunk partners, normalize, hi/lo, transpose, write ----
  float plsum = (ls0 + ls1) + (ls2 + ls3);
  plsum += __shfl_xor(plsum, 32);

  float* PO = (float*)smem;            // [2][32][64] f32 = 16KB (over Kf, dead)
  float* PL = (float*)(smem + 16384);  // [2][64]
  bf16*  Tr = (bf16*)(smem + 17408);   // [64][72] bf16 = 9216B

  if (w >= 2) {
    const int pw = w - 2;
    #pragma unroll
    for (int r = 0; r < 16; ++r) {
      PO[(pw * 32 + r) * 64 + lane]      = o0[r];
      PO[(pw * 32 + 16 + r) * 64 + lane] = o1[r];
    }
    PL[pw * 64 + lane] = plsum;
  }
  __syncthreads();

  if (w < 2) {
    #pragma unroll
    for (int r = 0; r < 16; ++r) {
      o0[r] += PO[(w * 32 + r) * 64 + lane];
      o1[r] += PO[(w * 32 + 16 + r) * 64 + lane];
    }
    plsum += PL[w * 64 + lane];
    const float inv = 1.f / plsum;
    #pragma unroll
    for (int r = 0; r < 16; ++r) { o0[r] *= inv; o1[r] *= inv; }
  }
  __syncthreads();

  if (w < 2) {
    #pragma unroll
    for (int r = 0; r < 16; ++r) {
      const int dr = (r & 3) + 8 * (r >> 2) + lh4;
      Tr[(w * 32 + l31) * 72 + dr]      = (bf16)o0[r];
      Tr[(w * 32 + l31) * 72 + 32 + dr] = (bf16)o1[r];
    }
  }
  __syncthreads();
  if (tid < 128) {
    const int rloc = tid >> 1, half = tid & 1;
    bf16* dst = ctxh + ((size_t)bh * SLEN + q0 + rloc) * 64 + half * 32;
    const bf16* srcp = Tr + rloc * 72 + half * 32;
    #pragma unroll
    for (int u = 0; u < 4; ++u) *(uint4v*)(dst + u * 8) = *(const uint4v*)(srcp + u * 8);
  }
  __syncthreads();
  if (w < 2) {
    #pragma unroll
    for (int r = 0; r < 16; ++r) {
      const int dr = (r & 3) + 8 * (r >> 2) + lh4;
      const float h0 = (float)(bf16)o0[r];
      const float h1 = (float)(bf16)o1[r];
      Tr[(w * 32 + l31) * 72 + dr]      = (bf16)(o0[r] - h0);
      Tr[(w * 32 + l31) * 72 + 32 + dr] = (bf16)(o1[r] - h1);
    }
  }
  __syncthreads();
  if (tid < 128) {
    const int rloc = tid >> 1, half = tid & 1;
    bf16* dst = ctxl + ((size_t)bh * SLEN + q0 + rloc) * 64 + half * 32;
    const bf16* srcp = Tr + rloc * 72 + half * 32;
    #pragma unroll
    for (int u = 0; u < 4; ++u) *(uint4v*)(dst + u * 8) = *(const uint4v*)(srcp + u * 8);
  }
}

// ---------------- kernel 5: output projection (hi/lo split GEMM) ----------------
__global__ __launch_bounds__(256, 2) void out_proj(
    const bf16* __restrict__ CH, const bf16* __restrict__ CL,
    const bf16* __restrict__ WH, const bf16* __restrict__ WL,
    const float* __restrict__ bo, float* __restrict__ out)
{
  __shared__ __align__(16) bf16 Af[2][4][4][64][8];  // 32KB
  const int tid = threadIdx.x, w = tid >> 6, lane = tid & 63, l31 = lane & 31, lh = lane >> 5;
  const int mt = blockIdx.x >> 3, nt = blockIdx.x & 7;
  const int bs0 = mt * 128, n0 = nt * 64;
  const int b = bs0 >> 12, sbase = bs0 & 4095;

  f32x16 a0, a1;
  #pragma unroll
  for (int r = 0; r < 16; ++r) { a0[r] = 0.f; a1[r] = 0.f; }

  for (int kk = 0; kk < 8; ++kk) {
    __syncthreads();
    #pragma unroll
    for (int qq = 0; qq < 8; ++qq) {
      const int fid = w * 8 + qq, pl = fid >> 4, mb = (fid >> 2) & 3, c = fid & 3;
      const bf16* src = (pl ? CL : CH) +
          ((size_t)(b * 8 + kk) * SLEN + sbase + 32 * mb + l31) * 64 + 16 * c + 8 * lh;
      cp16(src, &Af[pl][mb][c][0][0]);
    }
    __syncthreads();

    bf16x8 bh0[4], bl0[4], bh1[4], bl1[4], ah[4], al[4];
    #pragma unroll
    for (int c = 0; c < 4; ++c) {
      const size_t o0off = (size_t)(n0 + l31) * EMB + kk * 64 + 16 * c + 8 * lh;
      const size_t o1off = (size_t)(n0 + l31 + 32) * EMB + kk * 64 + 16 * c + 8 * lh;
      bh0[c] = *(const bf16x8*)(WH + o0off);
      bl0[c] = *(const bf16x8*)(WL + o0off);
      bh1[c] = *(const bf16x8*)(WH + o1off);
      bl1[c] = *(const bf16x8*)(WL + o1off);
      ah[c] = *(const bf16x8*)(&Af[0][w][c][lane][0]);
      al[c] = *(const bf16x8*)(&Af[1][w][c][lane][0]);
    }
    #pragma unroll
    for (int c = 0; c < 4; ++c) {
      a0 = mfma32(ah[c], bh0[c], a0);
      a0 = mfma32(ah[c], bl0[c], a0);
      a0 = mfma32(al[c], bh0[c], a0);
      a1 = mfma32(ah[c], bh1[c], a1);
      a1 = mfma32(ah[c], bl1[c], a1);
      a1 = mfma32(al[c], bh1[c], a1);
    }
  }

  const float bv0 = bo[n0 + l31], bv1 = bo[n0 + l31 + 32];
  #pragma unroll
  for (int r = 0; r < 16; ++r) {
    const int row = bs0 + w * 32 + (r & 3) + 8 * (r >> 2) + 4 * lh;
    out[(size_t)row * EMB + n0 + l31]      = a0[r] + bv0;
    out[(size_t)row * EMB + n0 + l31 + 32] = a1[r] + bv1;
  }
}

// ---------------- launch ----------------
extern "C" void kernel_launch(void* const* d_in, const int* in_sizes, int n_in,
                              void* d_out, int out_size, void* d_ws, size_t ws_size,
                              hipStream_t stream)
{
  (void)in_sizes; (void)n_in; (void)out_size; (void)ws_size;
  const float* key   = (const float*)d_in[0];
  const float* query = (const float*)d_in[1];
  const float* value = (const float*)d_in[2];
  const int*   mask  = (const int*)d_in[3];
  const float* Wq    = (const float*)d_in[4];
  const float* Wk    = (const float*)d_in[5];
  const float* Wv    = (const float*)d_in[6];
  const float* Wo    = (const float*)d_in[7];
  const float* bo    = (const float*)d_in[8];
  float* out = (float*)d_out;

  char* ws = (char*)d_ws;                       // ~43.5 MB used
  bf16* Qb = (bf16*)(ws);                       // 8 MB  [BH][S][64]
  bf16* Kb = (bf16*)(ws + (8ull  << 20));       // 8 MB  [BH][S][64]
  bf16* VT = (bf16*)(ws + (16ull << 20));       // 8 MB  [BH][64][S]
  unsigned* MW = (unsigned*)(ws + (24ull << 20));  // 2 MB [lh][tile][q]
  bf16* CH = (bf16*)(ws + (26ull << 20));       // 8 MB  ctx hi
  bf16* CL = (bf16*)(ws + (34ull << 20));       // 8 MB  ctx lo
  bf16* WH = (bf16*)(ws + (42ull << 20));       // 512 KB
  bf16* WL = (bf16*)(ws + (42ull << 20) + (512ull << 10));

  proj_qkv<<<512, 256, 0, stream>>>(key, query, value, Wq, Wk, Wv, Qb, Kb, VT);
  pack_mask<<<1024, 256, 0, stream>>>(mask, MW);
  wo_split<<<256, 256, 0, stream>>>(Wo, WH, WL);
  attn_kernel<<<1024, 256, 0, stream>>>(Qb, Kb, VT, MW, CH, CL);
  out_proj<<<512, 256, 0, stream>>>(CH, CL, WH, WL, bo, out);
}